// Round 1
// baseline (2796.900 us; speedup 1.0000x reference)
//
#include <hip/hip_runtime.h>

// ---------------------------------------------------------------------------
// E-GraphSAGE forward, f32. Stages:
//   1. CSR build by dst (histogram + scan + fill)
//   2. agg1 [N,80]  = mean over incoming edges of [x[src](16) | ea(64)]
//   3. h1  [N,128]  = ReLU([x | agg1] @ W1 + b1)          (K=96)
//   4. agg2 [N,192] = mean over incoming edges of [h1[src](128) | ea(64)]
//   5. h2  [N,128]  = ReLU([h1 | agg2] @ W2 + b2)         (K=320)
//   6. out [E,1]    = MLP_320_128_64_1([h2[src] | h2[dst] | ea])
// ---------------------------------------------------------------------------

#define SCAN_T 1024

// edge_index may arrive as int32 or int64 depending on harness conversion.
__device__ __forceinline__ int ld_idx(const void* ei, long long pos, int is64) {
    if (is64) return (int)((const long long*)ei)[pos];
    return ((const int*)ei)[pos];
}

__global__ void detect64_kernel(const void* ei, int* flag) {
    if (threadIdx.x == 0 && blockIdx.x == 0) {
        const int* p = (const int*)ei;
        int is64 = 1;
        // int64 little-endian: odd int32 slots are the (zero) high words.
        // int32 data: those slots hold random node ids -> ~never all zero.
        for (int i = 0; i < 64; ++i) {
            if (p[2 * i + 1] != 0) { is64 = 0; break; }
        }
        *flag = is64;
    }
}

__global__ void hist_kernel(const void* ei, int E, int* cnt, const int* flag) {
    int is64 = *flag;
    for (int e = blockIdx.x * blockDim.x + threadIdx.x; e < E;
         e += gridDim.x * blockDim.x) {
        int d = ld_idx(ei, (long long)E + e, is64);
        atomicAdd(&cnt[d], 1);
    }
}

__global__ void scan_kernel(const int* cnt, int* row, int n) {
    __shared__ int ps[SCAN_T];
    int tid = threadIdx.x;
    int per = (n + SCAN_T - 1) / SCAN_T;
    int s0 = tid * per;
    int s1 = min(s0 + per, n);
    int s = 0;
    for (int i = s0; i < s1; ++i) s += cnt[i];
    ps[tid] = s;
    __syncthreads();
    // Hillis-Steele inclusive scan over the 1024 partials
    for (int off = 1; off < SCAN_T; off <<= 1) {
        int v = (tid >= off) ? ps[tid - off] : 0;
        __syncthreads();
        ps[tid] += v;
        __syncthreads();
    }
    int run = (tid == 0) ? 0 : ps[tid - 1];
    for (int i = s0; i < s1; ++i) { row[i] = run; run += cnt[i]; }
    if (s0 < n && s1 == n) row[n] = run;
}

__global__ void fill_kernel(const void* ei, int E, const int* row, int* cursor,
                            int* eids, const int* flag) {
    int is64 = *flag;
    for (int e = blockIdx.x * blockDim.x + threadIdx.x; e < E;
         e += gridDim.x * blockDim.x) {
        int d = ld_idx(ei, (long long)E + e, is64);
        int pos = atomicAdd(&cursor[d], 1);
        eids[row[d] + pos] = e;
    }
}

// One wave per node; lane covers feature j=lane and j=lane+64 (j<80).
__global__ void agg1_kernel(const void* ei, const float* __restrict__ x,
                            const float* __restrict__ ea, const int* row,
                            const int* eids, float* __restrict__ agg1, int N,
                            const int* flag) {
    int is64 = *flag;
    int node = blockIdx.x * 4 + (threadIdx.x >> 6);
    int lane = threadIdx.x & 63;
    if (node >= N) return;
    int r0 = row[node], r1 = row[node + 1];
    float a0 = 0.f, a1 = 0.f;
    for (int i = r0; i < r1; ++i) {
        int e = eids[i];
        int s = ld_idx(ei, e, is64);
        float v0 = (lane < 16) ? x[s * 16 + lane] : ea[e * 64 + (lane - 16)];
        a0 += v0;
        if (lane < 16) a1 += ea[e * 64 + 48 + lane];  // features 64..79
    }
    agg1[node * 80 + lane] = a0;
    if (lane < 16) agg1[node * 80 + 64 + lane] = a1;
}

// h1 = ReLU([x | agg1/deg] @ W1 + b1); 8 nodes per 128-thread block.
__global__ void update1_kernel(const float* __restrict__ x,
                               const float* __restrict__ agg1, const int* row,
                               const float* __restrict__ W1,
                               const float* __restrict__ b1,
                               float* __restrict__ h1, int N) {
    __shared__ float in_s[8][96];
    int base = blockIdx.x * 8;
    int tid = threadIdx.x;
    for (int idx = tid; idx < 8 * 96; idx += 128) {
        int i = idx / 96, k = idx % 96;
        int node = base + i;
        float v = 0.f;
        if (node < N) {
            if (k < 16) v = x[node * 16 + k];
            else {
                float inv = 1.f / fmaxf((float)(row[node + 1] - row[node]), 1.f);
                v = agg1[node * 80 + (k - 16)] * inv;
            }
        }
        in_s[i][k] = v;
    }
    __syncthreads();
    int j = tid;
    float acc[8];
#pragma unroll
    for (int i = 0; i < 8; ++i) acc[i] = 0.f;
    for (int k = 0; k < 96; ++k) {
        float w = W1[k * 128 + j];
#pragma unroll
        for (int i = 0; i < 8; ++i) acc[i] += in_s[i][k] * w;
    }
    float bj = b1[j];
#pragma unroll
    for (int i = 0; i < 8; ++i) {
        int node = base + i;
        if (node < N) h1[node * 128 + j] = fmaxf(acc[i] + bj, 0.f);
    }
}

// One wave per node; lane covers features lane, lane+64, lane+128 (of 192).
__global__ void agg2_kernel(const void* ei, const float* __restrict__ h1,
                            const float* __restrict__ ea, const int* row,
                            const int* eids, float* __restrict__ agg2, int N,
                            const int* flag) {
    int is64 = *flag;
    int node = blockIdx.x * 4 + (threadIdx.x >> 6);
    int lane = threadIdx.x & 63;
    if (node >= N) return;
    int r0 = row[node], r1 = row[node + 1];
    float a0 = 0.f, a1 = 0.f, a2 = 0.f;
    for (int i = r0; i < r1; ++i) {
        int e = eids[i];
        int s = ld_idx(ei, e, is64);
        a0 += h1[s * 128 + lane];
        a1 += h1[s * 128 + 64 + lane];
        a2 += ea[e * 64 + lane];
    }
    agg2[node * 192 + lane] = a0;
    agg2[node * 192 + 64 + lane] = a1;
    agg2[node * 192 + 128 + lane] = a2;
}

// h2 = ReLU([h1 | agg2/deg] @ W2 + b2); K=320.
__global__ void update2_kernel(const float* __restrict__ h1,
                               const float* __restrict__ agg2, const int* row,
                               const float* __restrict__ W2,
                               const float* __restrict__ b2,
                               float* __restrict__ h2, int N) {
    __shared__ float in_s[8][320];
    int base = blockIdx.x * 8;
    int tid = threadIdx.x;
    for (int idx = tid; idx < 8 * 320; idx += 128) {
        int i = idx / 320, k = idx % 320;
        int node = base + i;
        float v = 0.f;
        if (node < N) {
            if (k < 128) v = h1[node * 128 + k];
            else {
                float inv = 1.f / fmaxf((float)(row[node + 1] - row[node]), 1.f);
                v = agg2[node * 192 + (k - 128)] * inv;
            }
        }
        in_s[i][k] = v;
    }
    __syncthreads();
    int j = tid;
    float acc[8];
#pragma unroll
    for (int i = 0; i < 8; ++i) acc[i] = 0.f;
    for (int k = 0; k < 320; ++k) {
        float w = W2[k * 128 + j];
#pragma unroll
        for (int i = 0; i < 8; ++i) acc[i] += in_s[i][k] * w;
    }
    float bj = b2[j];
#pragma unroll
    for (int i = 0; i < 8; ++i) {
        int node = base + i;
        if (node < N) h2[node * 128 + j] = fmaxf(acc[i] + bj, 0.f);
    }
}

// Per-edge MLP: [h2[src]|h2[dst]|ea](320) -> 128 -> 64 -> 1. 8 edges/block.
__global__ void classifier_kernel(const void* ei, const float* __restrict__ h2,
                                  const float* __restrict__ ea,
                                  const float* __restrict__ Wc1,
                                  const float* __restrict__ bc1,
                                  const float* __restrict__ Wc2,
                                  const float* __restrict__ bc2,
                                  const float* __restrict__ Wc3,
                                  const float* __restrict__ bc3,
                                  float* __restrict__ out, int E,
                                  const int* flag) {
    __shared__ float rep[8][320];
    __shared__ float z1s[8][128];
    __shared__ float z2s[8][64];
    int is64 = *flag;
    int base = blockIdx.x * 8;
    int tid = threadIdx.x;
    for (int idx = tid; idx < 8 * 320; idx += 128) {
        int i = idx / 320, k = idx % 320;
        int e = base + i;
        float v = 0.f;
        if (e < E) {
            if (k < 128) {
                int s = ld_idx(ei, e, is64);
                v = h2[s * 128 + k];
            } else if (k < 256) {
                int d = ld_idx(ei, (long long)E + e, is64);
                v = h2[d * 128 + (k - 128)];
            } else {
                v = ea[e * 64 + (k - 256)];
            }
        }
        rep[i][k] = v;
    }
    __syncthreads();
    {   // z1 = ReLU(rep @ Wc1 + bc1): thread j computes col j for 8 edges
        int j = tid;
        float acc[8];
#pragma unroll
        for (int i = 0; i < 8; ++i) acc[i] = 0.f;
        for (int k = 0; k < 320; ++k) {
            float w = Wc1[k * 128 + j];
#pragma unroll
            for (int i = 0; i < 8; ++i) acc[i] += rep[i][k] * w;
        }
        float bj = bc1[j];
#pragma unroll
        for (int i = 0; i < 8; ++i) z1s[i][j] = fmaxf(acc[i] + bj, 0.f);
    }
    __syncthreads();
    {   // z2 = ReLU(z1 @ Wc2 + bc2): wave w handles edges 4w..4w+3
        int half = tid >> 6, jj = tid & 63;
        float acc2[4];
#pragma unroll
        for (int ii = 0; ii < 4; ++ii) acc2[ii] = 0.f;
        for (int k = 0; k < 128; ++k) {
            float wv = Wc2[k * 64 + jj];
#pragma unroll
            for (int ii = 0; ii < 4; ++ii)
                acc2[ii] += z1s[half * 4 + ii][k] * wv;
        }
        float bj = bc2[jj];
#pragma unroll
        for (int ii = 0; ii < 4; ++ii)
            z2s[half * 4 + ii][jj] = fmaxf(acc2[ii] + bj, 0.f);
    }
    __syncthreads();
    {   // out = z2 @ Wc3 + bc3: 16 lanes reduce one edge
        int grp = tid >> 4, l = tid & 15;
        float p = 0.f;
#pragma unroll
        for (int t = 0; t < 4; ++t) p += z2s[grp][l + 16 * t] * Wc3[l + 16 * t];
        p += __shfl_down(p, 8, 16);
        p += __shfl_down(p, 4, 16);
        p += __shfl_down(p, 2, 16);
        p += __shfl_down(p, 1, 16);
        int e = base + grp;
        if (l == 0 && e < E) out[e] = p + bc3[0];
    }
}

extern "C" void kernel_launch(void* const* d_in, const int* in_sizes, int n_in,
                              void* d_out, int out_size, void* d_ws,
                              size_t ws_size, hipStream_t stream) {
    const float* x   = (const float*)d_in[0];
    const void*  ei  = d_in[1];
    const float* ea  = (const float*)d_in[2];
    const float* W1  = (const float*)d_in[3];
    const float* b1  = (const float*)d_in[4];
    const float* W2  = (const float*)d_in[5];
    const float* b2  = (const float*)d_in[6];
    const float* Wc1 = (const float*)d_in[7];
    const float* bc1 = (const float*)d_in[8];
    const float* Wc2 = (const float*)d_in[9];
    const float* bc2 = (const float*)d_in[10];
    const float* Wc3 = (const float*)d_in[11];
    const float* bc3 = (const float*)d_in[12];
    float* out = (float*)d_out;

    int N = in_sizes[0] / 16;   // 50000
    int E = in_sizes[2] / 64;   // 800000

    char* ws = (char*)d_ws;
    size_t off = 0;
    auto alloc = [&](size_t bytes) {
        void* p = ws + off;
        off += (bytes + 511) & ~(size_t)511;
        return p;
    };
    int*   cnt    = (int*)alloc((size_t)N * 4);
    int*   cursor = (int*)alloc((size_t)N * 4);
    int*   row    = (int*)alloc((size_t)(N + 1) * 4);
    int*   eids   = (int*)alloc((size_t)E * 4);
    int*   flag   = (int*)alloc(4);
    float* agg1   = (float*)alloc((size_t)N * 80 * 4);
    float* h1     = (float*)alloc((size_t)N * 128 * 4);
    float* agg2   = (float*)alloc((size_t)N * 192 * 4);
    float* h2     = (float*)alloc((size_t)N * 128 * 4);
    (void)ws_size; (void)n_in; (void)out_size;

    hipMemsetAsync(cnt, 0, (size_t)N * 4, stream);
    hipMemsetAsync(cursor, 0, (size_t)N * 4, stream);

    detect64_kernel<<<1, 64, 0, stream>>>(ei, flag);
    hist_kernel<<<1024, 256, 0, stream>>>(ei, E, cnt, flag);
    scan_kernel<<<1, SCAN_T, 0, stream>>>(cnt, row, N);
    fill_kernel<<<1024, 256, 0, stream>>>(ei, E, row, cursor, eids, flag);
    agg1_kernel<<<(N + 3) / 4, 256, 0, stream>>>(ei, x, ea, row, eids, agg1, N, flag);
    update1_kernel<<<(N + 7) / 8, 128, 0, stream>>>(x, agg1, row, W1, b1, h1, N);
    agg2_kernel<<<(N + 3) / 4, 256, 0, stream>>>(ei, h1, ea, row, eids, agg2, N, flag);
    update2_kernel<<<(N + 7) / 8, 128, 0, stream>>>(h1, agg2, row, W2, b2, h2, N);
    classifier_kernel<<<(E + 7) / 8, 128, 0, stream>>>(ei, h2, ea, Wc1, bc1, Wc2,
                                                       bc2, Wc3, bc3, out, E, flag);
}

// Round 4
// 1729.081 us; speedup vs baseline: 1.6176x; 1.6176x over previous
//
#include <hip/hip_runtime.h>

// ---------------------------------------------------------------------------
// E-GraphSAGE forward, f32. Stages:
//   1. CSR build by dst (histogram + scan + fill)
//   2. agg1 [N,80]  = mean over incoming edges of [x[src](16) | ea(64)]
//   3. h1  [N,128]  = ReLU([x | agg1] @ W1 + b1)          (K=96)
//   4. agg2 [N,192] = mean over incoming edges of [h1[src](128) | ea(64)]
//   5. h2  [N,128]  = ReLU([h1 | agg2] @ W2 + b2)         (K=320)
//   6. out [E,1]    = fused edge MLP 320->128->64->1, register-tiled
// ---------------------------------------------------------------------------

#define SCAN_T 1024

// edge_index may arrive as int32 or int64 depending on harness conversion.
__device__ __forceinline__ int ld_idx(const void* ei, long long pos, int is64) {
    if (is64) return (int)((const long long*)ei)[pos];
    return ((const int*)ei)[pos];
}

__global__ void detect64_kernel(const void* ei, int* flag) {
    if (threadIdx.x == 0 && blockIdx.x == 0) {
        const int* p = (const int*)ei;
        int is64 = 1;
        for (int i = 0; i < 64; ++i) {
            if (p[2 * i + 1] != 0) { is64 = 0; break; }
        }
        *flag = is64;
    }
}

__global__ void hist_kernel(const void* ei, int E, int* cnt, const int* flag) {
    int is64 = *flag;
    for (int e = blockIdx.x * blockDim.x + threadIdx.x; e < E;
         e += gridDim.x * blockDim.x) {
        int d = ld_idx(ei, (long long)E + e, is64);
        atomicAdd(&cnt[d], 1);
    }
}

__global__ void scan_kernel(const int* cnt, int* row, int n) {
    __shared__ int ps[SCAN_T];
    int tid = threadIdx.x;
    int per = (n + SCAN_T - 1) / SCAN_T;
    int s0 = tid * per;
    int s1 = min(s0 + per, n);
    int s = 0;
    for (int i = s0; i < s1; ++i) s += cnt[i];
    ps[tid] = s;
    __syncthreads();
    for (int off = 1; off < SCAN_T; off <<= 1) {
        int v = (tid >= off) ? ps[tid - off] : 0;
        __syncthreads();
        ps[tid] += v;
        __syncthreads();
    }
    int run = (tid == 0) ? 0 : ps[tid - 1];
    for (int i = s0; i < s1; ++i) { row[i] = run; run += cnt[i]; }
    if (s0 < n && s1 == n) row[n] = run;
}

__global__ void fill_kernel(const void* ei, int E, const int* row, int* cursor,
                            int* eids, const int* flag) {
    int is64 = *flag;
    for (int e = blockIdx.x * blockDim.x + threadIdx.x; e < E;
         e += gridDim.x * blockDim.x) {
        int d = ld_idx(ei, (long long)E + e, is64);
        int pos = atomicAdd(&cursor[d], 1);
        eids[row[d] + pos] = e;
    }
}

__global__ void agg1_kernel(const void* ei, const float* __restrict__ x,
                            const float* __restrict__ ea, const int* row,
                            const int* eids, float* __restrict__ agg1, int N,
                            const int* flag) {
    int is64 = *flag;
    int node = blockIdx.x * 4 + (threadIdx.x >> 6);
    int lane = threadIdx.x & 63;
    if (node >= N) return;
    int r0 = row[node], r1 = row[node + 1];
    float a0 = 0.f, a1 = 0.f;
    for (int i = r0; i < r1; ++i) {
        int e = eids[i];
        int s = ld_idx(ei, e, is64);
        float v0 = (lane < 16) ? x[s * 16 + lane] : ea[e * 64 + (lane - 16)];
        a0 += v0;
        if (lane < 16) a1 += ea[e * 64 + 48 + lane];
    }
    agg1[node * 80 + lane] = a0;
    if (lane < 16) agg1[node * 80 + 64 + lane] = a1;
}

__global__ void update1_kernel(const float* __restrict__ x,
                               const float* __restrict__ agg1, const int* row,
                               const float* __restrict__ W1,
                               const float* __restrict__ b1,
                               float* __restrict__ h1, int N) {
    __shared__ float in_s[8][96];
    int base = blockIdx.x * 8;
    int tid = threadIdx.x;
    for (int idx = tid; idx < 8 * 96; idx += 128) {
        int i = idx / 96, k = idx % 96;
        int node = base + i;
        float v = 0.f;
        if (node < N) {
            if (k < 16) v = x[node * 16 + k];
            else {
                float inv = 1.f / fmaxf((float)(row[node + 1] - row[node]), 1.f);
                v = agg1[node * 80 + (k - 16)] * inv;
            }
        }
        in_s[i][k] = v;
    }
    __syncthreads();
    int j = tid;
    float acc[8];
#pragma unroll
    for (int i = 0; i < 8; ++i) acc[i] = 0.f;
    for (int k = 0; k < 96; ++k) {
        float w = W1[k * 128 + j];
#pragma unroll
        for (int i = 0; i < 8; ++i) acc[i] += in_s[i][k] * w;
    }
    float bj = b1[j];
#pragma unroll
    for (int i = 0; i < 8; ++i) {
        int node = base + i;
        if (node < N) h1[node * 128 + j] = fmaxf(acc[i] + bj, 0.f);
    }
}

__global__ void agg2_kernel(const void* ei, const float* __restrict__ h1,
                            const float* __restrict__ ea, const int* row,
                            const int* eids, float* __restrict__ agg2, int N,
                            const int* flag) {
    int is64 = *flag;
    int node = blockIdx.x * 4 + (threadIdx.x >> 6);
    int lane = threadIdx.x & 63;
    if (node >= N) return;
    int r0 = row[node], r1 = row[node + 1];
    float a0 = 0.f, a1 = 0.f, a2 = 0.f;
    for (int i = r0; i < r1; ++i) {
        int e = eids[i];
        int s = ld_idx(ei, e, is64);
        a0 += h1[s * 128 + lane];
        a1 += h1[s * 128 + 64 + lane];
        a2 += ea[e * 64 + lane];
    }
    agg2[node * 192 + lane] = a0;
    agg2[node * 192 + 64 + lane] = a1;
    agg2[node * 192 + 128 + lane] = a2;
}

__global__ void update2_kernel(const float* __restrict__ h1,
                               const float* __restrict__ agg2, const int* row,
                               const float* __restrict__ W2,
                               const float* __restrict__ b2,
                               float* __restrict__ h2, int N) {
    __shared__ float in_s[8][320];
    int base = blockIdx.x * 8;
    int tid = threadIdx.x;
    for (int idx = tid; idx < 8 * 320; idx += 128) {
        int i = idx / 320, k = idx % 320;
        int node = base + i;
        float v = 0.f;
        if (node < N) {
            if (k < 128) v = h1[node * 128 + k];
            else {
                float inv = 1.f / fmaxf((float)(row[node + 1] - row[node]), 1.f);
                v = agg2[node * 192 + (k - 128)] * inv;
            }
        }
        in_s[i][k] = v;
    }
    __syncthreads();
    int j = tid;
    float acc[8];
#pragma unroll
    for (int i = 0; i < 8; ++i) acc[i] = 0.f;
    for (int k = 0; k < 320; ++k) {
        float w = W2[k * 128 + j];
#pragma unroll
        for (int i = 0; i < 8; ++i) acc[i] += in_s[i][k] * w;
    }
    float bj = b2[j];
#pragma unroll
    for (int i = 0; i < 8; ++i) {
        int node = base + i;
        if (node < N) h2[node * 128 + j] = fmaxf(acc[i] + bj, 0.f);
    }
}

// ---------------------------------------------------------------------------
// Fused edge classifier: 64 edges/block, 256 threads.
// Phase A: z1[64][128] = ReLU(rep @ Wc1 + bc1), rep gathered transposed to LDS,
//          thread tile 8 edges x 4 cols -> 32 FMA per 3 ds_read_b128.
// Phase B: z2[64][64]  = ReLU(z1 @ Wc2 + bc2), thread tile 4x4.
// Phase C: out = z2 @ Wc3 + bc3, 4-lane shuffle reduce.
// ---------------------------------------------------------------------------
__global__ __launch_bounds__(256, 2) void classifier_kernel(
    const void* ei, const float* __restrict__ h2, const float* __restrict__ ea,
    const float* __restrict__ Wc1, const float* __restrict__ bc1,
    const float* __restrict__ Wc2, const float* __restrict__ bc2,
    const float* __restrict__ Wc3, const float* __restrict__ bc3,
    float* __restrict__ out, int E, const int* flag) {
    __shared__ float wbuf[4096];      // 16 KB   weight K-tile
    __shared__ float rT[32][68];      // 8.7 KB  rep^T K-tile (pad 68 -> 16B rows)
    __shared__ float z1T[128][68];    // 34.8 KB z1 transposed
    __shared__ float z2T[64][68];     // 17.4 KB z2 transposed

    const int tid = threadIdx.x;
    const int base = blockIdx.x * 64;
    const int is64 = *flag;

    // ---------------- Phase A ----------------
    float acc[8][4];
#pragma unroll
    for (int i = 0; i < 8; ++i)
#pragma unroll
        for (int j = 0; j < 4; ++j) acc[i][j] = 0.f;

    const int cgrp = tid & 31, rgrp = tid >> 5;     // compute mapping
    const int j0 = cgrp * 4, e0 = rgrp * 8;
    const int el = tid & 63, seg = tid >> 6;        // staging mapping
    const int kk0 = seg * 8;
    const int eg = min(base + el, E - 1);

    for (int kt = 0; kt < 10; ++kt) {
        const int kbase = kt * 32;
        // stage Wc1 rows [kbase, kbase+32) x 128 cols (contiguous 4096 floats)
#pragma unroll
        for (int i = 0; i < 16; ++i) {
            int idx = tid + i * 256;
            wbuf[idx] = Wc1[kbase * 128 + idx];
        }
        // stage rep^T: this wave's 8-k segment for 64 edges
        {
            const int kb = kbase + kk0;
            const float* p;
            if (kb < 128) {
                int s = ld_idx(ei, eg, is64);
                p = h2 + (size_t)s * 128 + kb;
            } else if (kb < 256) {
                int d = ld_idx(ei, (long long)E + eg, is64);
                p = h2 + (size_t)d * 128 + (kb - 128);
            } else {
                p = ea + (size_t)eg * 64 + (kb - 256);
            }
            float4 v0 = *(const float4*)p;
            float4 v1 = *(const float4*)(p + 4);
            rT[kk0 + 0][el] = v0.x; rT[kk0 + 1][el] = v0.y;
            rT[kk0 + 2][el] = v0.z; rT[kk0 + 3][el] = v0.w;
            rT[kk0 + 4][el] = v1.x; rT[kk0 + 5][el] = v1.y;
            rT[kk0 + 6][el] = v1.z; rT[kk0 + 7][el] = v1.w;
        }
        __syncthreads();
#pragma unroll 4
        for (int kk = 0; kk < 32; ++kk) {
            float4 w = *(const float4*)&wbuf[kk * 128 + j0];
            float4 ra = *(const float4*)&rT[kk][e0];
            float4 rb = *(const float4*)&rT[kk][e0 + 4];
            float rv[8] = {ra.x, ra.y, ra.z, ra.w, rb.x, rb.y, rb.z, rb.w};
            float wv[4] = {w.x, w.y, w.z, w.w};
#pragma unroll
            for (int i = 0; i < 8; ++i)
#pragma unroll
                for (int j = 0; j < 4; ++j) acc[i][j] += rv[i] * wv[j];
        }
        __syncthreads();
    }
    // epilogue A: bias + ReLU -> z1T
    {
        float4 b = *(const float4*)&bc1[j0];
        float bv[4] = {b.x, b.y, b.z, b.w};
#pragma unroll
        for (int j = 0; j < 4; ++j) {
#pragma unroll
            for (int i = 0; i < 8; ++i)
                z1T[j0 + j][e0 + i] = fmaxf(acc[i][j] + bv[j], 0.f);
        }
    }
    __syncthreads();

    // ---------------- Phase B ----------------
    float acc2[4][4];
#pragma unroll
    for (int i = 0; i < 4; ++i)
#pragma unroll
        for (int j = 0; j < 4; ++j) acc2[i][j] = 0.f;
    const int jgB = tid & 15, rB = tid >> 4;
    const int j0b = jgB * 4, e0b = rB * 4;

    for (int half = 0; half < 2; ++half) {
        // stage Wc2 rows [half*64, half*64+64) x 64 cols (4096 floats)
#pragma unroll
        for (int i = 0; i < 16; ++i) {
            int idx = tid + i * 256;
            wbuf[idx] = Wc2[half * 4096 + idx];
        }
        __syncthreads();
#pragma unroll 4
        for (int kk = 0; kk < 64; ++kk) {
            float4 w = *(const float4*)&wbuf[kk * 64 + j0b];
            float4 a = *(const float4*)&z1T[half * 64 + kk][e0b];
            float av[4] = {a.x, a.y, a.z, a.w};
            float wv[4] = {w.x, w.y, w.z, w.w};
#pragma unroll
            for (int i = 0; i < 4; ++i)
#pragma unroll
                for (int j = 0; j < 4; ++j) acc2[i][j] += av[i] * wv[j];
        }
        __syncthreads();
    }
    // epilogue B: bias + ReLU -> z2T
    {
        float4 b = *(const float4*)&bc2[j0b];
        float bv[4] = {b.x, b.y, b.z, b.w};
#pragma unroll
        for (int j = 0; j < 4; ++j) {
            float4 v;
            v.x = fmaxf(acc2[0][j] + bv[j], 0.f);
            v.y = fmaxf(acc2[1][j] + bv[j], 0.f);
            v.z = fmaxf(acc2[2][j] + bv[j], 0.f);
            v.w = fmaxf(acc2[3][j] + bv[j], 0.f);
            *(float4*)&z2T[j0b + j][e0b] = v;
        }
    }
    __syncthreads();

    // ---------------- Phase C ----------------
    {
        const int e = tid >> 2, l = tid & 3;
        float p = 0.f;
#pragma unroll
        for (int i = 0; i < 16; ++i) {
            int k = l * 16 + i;
            p += z2T[k][e] * Wc3[k];
        }
        p += __shfl_xor(p, 1, 4);
        p += __shfl_xor(p, 2, 4);
        if (l == 0 && base + e < E) out[base + e] = p + bc3[0];
    }
}

extern "C" void kernel_launch(void* const* d_in, const int* in_sizes, int n_in,
                              void* d_out, int out_size, void* d_ws,
                              size_t ws_size, hipStream_t stream) {
    const float* x   = (const float*)d_in[0];
    const void*  ei  = d_in[1];
    const float* ea  = (const float*)d_in[2];
    const float* W1  = (const float*)d_in[3];
    const float* b1  = (const float*)d_in[4];
    const float* W2  = (const float*)d_in[5];
    const float* b2  = (const float*)d_in[6];
    const float* Wc1 = (const float*)d_in[7];
    const float* bc1 = (const float*)d_in[8];
    const float* Wc2 = (const float*)d_in[9];
    const float* bc2 = (const float*)d_in[10];
    const float* Wc3 = (const float*)d_in[11];
    const float* bc3 = (const float*)d_in[12];
    float* out = (float*)d_out;

    int N = in_sizes[0] / 16;   // 50000
    int E = in_sizes[2] / 64;   // 800000

    char* ws = (char*)d_ws;
    size_t off = 0;
    auto alloc = [&](size_t bytes) {
        void* p = ws + off;
        off += (bytes + 511) & ~(size_t)511;
        return p;
    };
    int*   cnt    = (int*)alloc((size_t)N * 4);
    int*   cursor = (int*)alloc((size_t)N * 4);
    int*   row    = (int*)alloc((size_t)(N + 1) * 4);
    int*   eids   = (int*)alloc((size_t)E * 4);
    int*   flag   = (int*)alloc(4);
    float* agg1   = (float*)alloc((size_t)N * 80 * 4);
    float* h1     = (float*)alloc((size_t)N * 128 * 4);
    float* agg2   = (float*)alloc((size_t)N * 192 * 4);
    float* h2     = (float*)alloc((size_t)N * 128 * 4);
    (void)ws_size; (void)n_in; (void)out_size;

    hipMemsetAsync(cnt, 0, (size_t)N * 4, stream);
    hipMemsetAsync(cursor, 0, (size_t)N * 4, stream);

    detect64_kernel<<<1, 64, 0, stream>>>(ei, flag);
    hist_kernel<<<1024, 256, 0, stream>>>(ei, E, cnt, flag);
    scan_kernel<<<1, SCAN_T, 0, stream>>>(cnt, row, N);
    fill_kernel<<<1024, 256, 0, stream>>>(ei, E, row, cursor, eids, flag);
    agg1_kernel<<<(N + 3) / 4, 256, 0, stream>>>(ei, x, ea, row, eids, agg1, N, flag);
    update1_kernel<<<(N + 7) / 8, 128, 0, stream>>>(x, agg1, row, W1, b1, h1, N);
    agg2_kernel<<<(N + 3) / 4, 256, 0, stream>>>(ei, h1, ea, row, eids, agg2, N, flag);
    update2_kernel<<<(N + 7) / 8, 128, 0, stream>>>(h1, agg2, row, W2, b2, h2, N);
    classifier_kernel<<<(E + 63) / 64, 256, 0, stream>>>(ei, h2, ea, Wc1, bc1,
                                                         Wc2, bc2, Wc3, bc3,
                                                         out, E, flag);
}